// Round 14
// baseline (329.818 us; speedup 1.0000x reference)
//
#include <hip/hip_runtime.h>
#include <hip/hip_bf16.h>
#include <stdint.h>
#include <stddef.h>

typedef __attribute__((ext_vector_type(8))) short bf16x8;       // 4-VGPR MFMA A/B frag (8 bf16)
typedef __attribute__((ext_vector_type(8))) unsigned short u16x8;
typedef __attribute__((ext_vector_type(4))) float f32x4;
typedef __attribute__((ext_vector_type(16))) float f32x16;      // 32x32 MFMA C/D frag

#define TT 1024

__device__ __forceinline__ unsigned short f2bf(float f){
  unsigned u = __builtin_bit_cast(unsigned, f);
  unsigned r = 0x7fffu + ((u >> 16) & 1u);
  return (unsigned short)((u + r) >> 16);
}
__device__ __forceinline__ float bf2f(unsigned short s){
  unsigned u = ((unsigned)s) << 16;
  return __builtin_bit_cast(float, u);
}
// async global->LDS, 16B per lane. LDS dest must be tid-linear (base + lane*16).
__device__ __forceinline__ void gload16(const unsigned short* g, unsigned short* l){
  __builtin_amdgcn_global_load_lds(
      (const __attribute__((address_space(1))) void*)g,
      (__attribute__((address_space(3))) void*)l, 16, 0, 0);
}

#define MFMA32(a, b, c) __builtin_amdgcn_mfma_f32_32x32x16_bf16((a), (b), (c), 0, 0, 0)
#define MFMA_B16(a, b, c) __builtin_amdgcn_mfma_f32_16x16x32_bf16((a), (b), (c), 0, 0, 0)

// ==== prep2: blocks 0..511 = x-cast + router + rope-table;  512..16895 = weight transposes ====
__global__ __launch_bounds__(256) void prep2_kernel(const float* __restrict__ x,
                                                    const float* __restrict__ wr,
                                                    const float* __restrict__ wqkv,
                                                    const float* __restrict__ wout,
                                                    unsigned short* __restrict__ x_bf,
                                                    float* __restrict__ gate,
                                                    unsigned char* __restrict__ heads4,
                                                    float* __restrict__ tab,
                                                    unsigned short* __restrict__ wqkvT,
                                                    unsigned short* __restrict__ woutT){
  __shared__ float xc[8 * 256];
  __shared__ float red[8 * 8 * 32];
  __shared__ float tile[32][33];
  const int tid = threadIdx.x;

  if (blockIdx.x >= 512){
    // ---- weight transpose+cast path ----
    int tb = blockIdx.x - 512;            // 0..16383
    int bx = tb & 255, by = tb >> 8;      // bx: 0..255 (192 qkv + 64 out), by: 0..63
    const float* in; unsigned short* out; int C;
    if (bx < 192){ in = wqkv; out = wqkvT; C = 6144; }
    else         { in = wout; out = woutT; C = 2048; bx -= 192; }
    const int R = 2048;
    int c0 = bx * 32, r0 = by * 32;
    int tx = tid & 31, ty = tid >> 5;     // 32 x 8
    for (int i = ty; i < 32; i += 8)
      tile[i][tx] = in[(size_t)(r0 + i) * C + c0 + tx];
    __syncthreads();
    for (int i = ty; i < 32; i += 8)
      out[(size_t)(c0 + i) * R + r0 + tx] = f2bf(tile[tx][i]);
    return;
  }

  // ---- prep path ----
  const int tok0 = blockIdx.x * 8;
  const int p = tid >> 5, h = tid & 31;

  if (blockIdx.x < 128){
    int i2 = blockIdx.x * 256 + tid;
    int pos = i2 >> 5, ii = i2 & 31;
    float freq = powf(10000.0f, -(float)ii / 32.0f);
    float ang = (float)pos * freq;
    tab[i2 * 2]     = cosf(ang);
    tab[i2 * 2 + 1] = sinf(ang);
  }

  float acc[8] = {0.f,0.f,0.f,0.f,0.f,0.f,0.f,0.f};
  for (int kb = 0; kb < 8; kb++){
    __syncthreads();
    {
      int tok = tid >> 5, e = (tid & 31) * 8;
      const float* xp = x + (size_t)(tok0 + tok) * 2048 + kb * 256 + e;
      float4 v0 = *(const float4*)xp, v1 = *(const float4*)(xp + 4);
      float vals[8] = {v0.x, v0.y, v0.z, v0.w, v1.x, v1.y, v1.z, v1.w};
      u16x8 ob;
      #pragma unroll
      for (int jj = 0; jj < 8; jj++) ob[jj] = f2bf(vals[jj]);
      *(u16x8*)(x_bf + (size_t)(tok0 + tok) * 2048 + kb * 256 + e) = ob;
      #pragma unroll
      for (int jj = 0; jj < 8; jj++) xc[tok * 256 + e + jj] = vals[jj];
    }
    __syncthreads();
    const float* wp = wr + (size_t)(kb * 256 + p * 32) * 32 + h;
    #pragma unroll 4
    for (int j = 0; j < 32; j++){
      float wv = wp[j * 32];
      #pragma unroll
      for (int tok = 0; tok < 8; tok++)
        acc[tok] += xc[tok * 256 + p * 32 + j] * wv;
    }
  }
  #pragma unroll
  for (int tok = 0; tok < 8; tok++) red[(p * 8 + tok) * 32 + h] = acc[tok];
  __syncthreads();
  {
    int lane = tid & 63;
    int tok = (tid >> 6) * 2 + (lane >> 5);
    int hh = lane & 31;
    float logit = 0.f;
    #pragma unroll
    for (int pp = 0; pp < 8; pp++) logit += red[(pp * 8 + tok) * 32 + hh];
    float m = logit;
    #pragma unroll
    for (int s = 16; s >= 1; s >>= 1) m = fmaxf(m, __shfl_xor(m, s));
    float e = __expf(logit - m);
    float sum = e;
    #pragma unroll
    for (int s = 16; s >= 1; s >>= 1) sum += __shfl_xor(sum, s);
    float prob = e / sum;
    float v = logit; int sel = 0;
    #pragma unroll
    for (int rr2 = 0; rr2 < 4; rr2++){
      float bv = v; int bi = hh;
      #pragma unroll
      for (int s = 16; s >= 1; s >>= 1){
        float ov = __shfl_xor(bv, s); int oi = __shfl_xor(bi, s);
        if (ov > bv || (ov == bv && oi < bi)) { bv = ov; bi = oi; }
      }
      if (hh == bi) { sel = 1; v = -3.4e38f; }
    }
    gate[(size_t)(tok0 + tok) * 32 + hh] = sel ? prob : 0.f;
    unsigned long long bal = __ballot(sel != 0);
    unsigned selmask = (unsigned)(bal >> ((lane >> 5) * 32));
    if (sel){
      int r = __popc(selmask & ((1u << hh) - 1u));
      heads4[(size_t)(tok0 + tok) * 4 + r] = (unsigned char)hh;
    }
  }
}

// ------- per-(b,h) active-token compaction; entry = tok | (rank<<10), order-preserving -------
__global__ void compact_kernel(const unsigned char* __restrict__ heads4,
                               unsigned short* __restrict__ idx, int* __restrict__ counts){
  int bh = blockIdx.x;
  int b = bh >> 5, h = bh & 31;
  int lane = threadIdx.x;
  int base = 0;
  for (int c = 0; c < 16; c++){
    int t = c * 64 + lane;
    unsigned u = ((const unsigned*)heads4)[b * 1024 + t];
    int r = -1;
    if (((u      ) & 255) == (unsigned)h) r = 0;
    else if (((u >>  8) & 255) == (unsigned)h) r = 1;
    else if (((u >> 16) & 255) == (unsigned)h) r = 2;
    else if (((u >> 24) & 255) == (unsigned)h) r = 3;
    bool act = (r >= 0);
    unsigned long long mask = __ballot(act);
    int pos = base + __popcll(mask & ((1ull << lane) - 1ull));
    if (act) idx[bh * 1024 + pos] = (unsigned short)(t | (r << 10));
    base += __popcll(mask);
  }
  if (lane == 0) counts[bh] = base;
}

// ==== super: blocks 0..511 = 32x32x16 KV GEMM (2 blocks/CU ring);  512..2559 = sparse Q GEMM ====
__global__ __launch_bounds__(256, 2) void super_kernel(const unsigned short* __restrict__ x_bf,
                                                       const unsigned short* __restrict__ wqkvT,
                                                       unsigned short* __restrict__ kbuf,
                                                       unsigned short* __restrict__ vt,
                                                       const float* __restrict__ tab,
                                                       const unsigned short* __restrict__ idx,
                                                       const int* __restrict__ counts,
                                                       unsigned short* __restrict__ qact){
  extern __shared__ unsigned short smem[];
  const int tid = threadIdx.x, lane = tid & 63;

  if (blockIdx.x < 512){
    // ---------------- KV GEMM path (round-13 gemmk, verbatim; + T5 setprio) ----------------
    const unsigned short* A  = x_bf;
    const unsigned short* Bt = wqkvT + (size_t)2048 * 2048;
    constexpr int MREP = 4;
    constexpr int BM = 256;
    constexpr int AU = MREP * 2048;
    constexpr int SLOT = AU + 4096;
    const int raw = blockIdx.x;
    const int tile = (raw & 7) * 64 + (raw >> 3);   // nblk = 512
    const int bn = tile >> 4, bm = tile & 15;       // nbm = 16
    const int K = 2048;

    const int wid = tid >> 6;
    const int wrow = wid >> 1, wcol = wid & 1;
    const int l31 = lane & 31, hi = lane >> 5;
    const int X = ((l31 >> 1) & 7) << 4;

    const unsigned short* gA[MREP];
    const unsigned short* gB[2];
    #pragma unroll
    for (int p = 0; p < MREP; p++){
      int L = tid * 16 + p * 4096;
      int line = L >> 7;
      int cs = (L & 127) ^ ((line & 7) << 4);
      gA[p] = A + (size_t)(bm * BM + line * 2 + (cs >> 6)) * K + ((cs & 63) >> 1);
    }
    #pragma unroll
    for (int p = 0; p < 2; p++){
      int L = tid * 16 + p * 4096;
      int line = L >> 7;
      int cs = (L & 127) ^ ((line & 7) << 4);
      gB[p] = Bt + (size_t)(bn * 128 + line * 2 + (cs >> 6)) * K + ((cs & 63) >> 1);
    }

    f32x16 acc[MREP][2];
    #pragma unroll
    for (int i = 0; i < MREP; i++)
      #pragma unroll
      for (int j = 0; j < 2; j++) acc[i][j] = f32x16{0,0,0,0,0,0,0,0,0,0,0,0,0,0,0,0};

    const int NT = K >> 5;   // BK = 32
    #pragma unroll
    for (int tt = 0; tt < 2; tt++){
      unsigned short* sb = smem + tt * SLOT;
      #pragma unroll
      for (int p = 0; p < MREP; p++) gload16(gA[p] + (size_t)tt * 32, sb + tid * 8 + p * 2048);
      #pragma unroll
      for (int p = 0; p < 2; p++)    gload16(gB[p] + (size_t)tt * 32, sb + AU + tid * 8 + p * 2048);
    }

    for (int t = 0; t < NT; ++t){
      if (t < NT - 1) asm volatile("s_waitcnt vmcnt(6)" ::: "memory");
      else            asm volatile("s_waitcnt vmcnt(0)" ::: "memory");
      __builtin_amdgcn_s_barrier();
      __builtin_amdgcn_sched_barrier(0);
      const unsigned short* bs = smem + (t % 3) * SLOT;
      unsigned short* ns = smem + ((t + 2) % 3) * SLOT;
      const bool st = (t + 2 < NT);
      #pragma unroll
      for (int ks = 0; ks < 2; ks++){
        const int bo = (((l31 & 1) * 64 + ks * 32 + hi * 16) ^ X) >> 1;
        bf16x8 av[MREP], bv[2];
        #pragma unroll
        for (int i = 0; i < MREP; i++)
          av[i] = *(const bf16x8*)(bs + (wrow * (MREP * 16) + i * 16 + (l31 >> 1)) * 64 + bo);
        #pragma unroll
        for (int j = 0; j < 2; j++)
          bv[j] = *(const bf16x8*)(bs + AU + (wcol * 32 + j * 16 + (l31 >> 1)) * 64 + bo);
        if (st){
          if (ks == 0){
            #pragma unroll
            for (int p = 0; p < 3; p++)
              gload16(gA[p] + (size_t)(t + 2) * 32, ns + tid * 8 + p * 2048);
          } else {
            gload16(gA[3] + (size_t)(t + 2) * 32, ns + tid * 8 + 3 * 2048);
            #pragma unroll
            for (int p = 0; p < 2; p++)
              gload16(gB[p] + (size_t)(t + 2) * 32, ns + AU + tid * 8 + p * 2048);
          }
        }
        __builtin_amdgcn_s_setprio(1);
        #pragma unroll
        for (int i = 0; i < MREP; i++){
          acc[i][0] = MFMA32(av[i], bv[0], acc[i][0]);
          acc[i][1] = MFMA32(av[i], bv[1], acc[i][1]);
        }
        __builtin_amdgcn_s_setprio(0);
      }
    }

    // 32x32 C/D: col = lane&31, row = (reg&3) + 8*(reg>>2) + 4*(lane>>5)
    if (bn < 16){
      #pragma unroll
      for (int i = 0; i < MREP; i++){
        #pragma unroll
        for (int j = 0; j < 2; j++){
          int col = bn * 128 + wcol * 64 + j * 32 + l31;
          int ii = (col & 63) >> 1;
          #pragma unroll
          for (int g = 0; g < 4; g++){
            #pragma unroll
            for (int rr = 0; rr < 4; rr++){
              int row = bm * BM + wrow * (BM / 2) + i * 32 + g * 8 + hi * 4 + rr;
              int pos = row & (TT - 1);
              const float* tp = tab + ((size_t)pos * 32 + ii) * 2;
              float c = tp[0], s = tp[1];
              float val = acc[i][j][g * 4 + rr];
              float pv = __shfl_xor(val, 1);
              float res = (lane & 1) ? (pv * s + val * c) : (val * c - pv * s);
              kbuf[(size_t)row * 2048 + col] = f2bf(res);
            }
          }
        }
      }
    } else {
      #pragma unroll
      for (int i = 0; i < MREP; i++){
        #pragma unroll
        for (int j = 0; j < 2; j++){
          int vcol = bn * 128 + wcol * 64 + j * 32 + l31 - 2048;
          int hh = vcol >> 6, d = vcol & 63;
          int row0 = bm * BM + wrow * (BM / 2) + i * 32 + hi * 4;
          int b = row0 >> 10, t0 = row0 & (TT - 1);
          #pragma unroll
          for (int g = 0; g < 4; g++){
            ushort4 pk;
            pk.x = f2bf(acc[i][j][g * 4 + 0]); pk.y = f2bf(acc[i][j][g * 4 + 1]);
            pk.z = f2bf(acc[i][j][g * 4 + 2]); pk.w = f2bf(acc[i][j][g * 4 + 3]);
            *(ushort4*)(vt + ((size_t)((b * 32 + hh) * 64 + d)) * TT + t0 + g * 8) = pk;
          }
        }
      }
    }
    return;
  }

  // ---------------- sparse Q GEMM path (round-13 qgemm, red[] in dynamic LDS) ----------------
  {
    float* red = (float*)smem;               // [4][64][64] = 64 KB
    const int r0 = blockIdx.x - 512;         // 0..2047
    const int bh = r0 >> 4, qt = r0 & 15;
    const int count = counts[bh];
    if (qt * 64 >= count) return;
    const int b = bh >> 5, h = bh & 31;
    const int w = tid >> 6;
    const int li = lane & 15, lg = lane >> 4;
    const int nvalid = min(64, count - qt * 64);
    const unsigned short* myidx = idx + bh * 1024 + qt * 64;

    int atok[4];
    #pragma unroll
    for (int ai = 0; ai < 4; ai++){
      int s = ai * 16 + li;
      atok[ai] = (s < nvalid) ? (myidx[s] & 1023) : 0;
    }
    const unsigned short* Bbase = wqkvT + (size_t)(h * 64) * 2048;

    f32x4 acc[4][4];
    #pragma unroll
    for (int i = 0; i < 4; i++)
      #pragma unroll
      for (int j = 0; j < 4; j++) acc[i][j] = f32x4{0.f, 0.f, 0.f, 0.f};

    const int k0w = w * 512;
    #pragma unroll 2
    for (int ks = 0; ks < 16; ks++){
      int k0 = k0w + ks * 32 + lg * 8;
      bf16x8 af[4], bw[4];
      #pragma unroll
      for (int ai = 0; ai < 4; ai++)
        af[ai] = *(const bf16x8*)(x_bf + (size_t)(b * 1024 + atok[ai]) * 2048 + k0);
      #pragma unroll
      for (int ni = 0; ni < 4; ni++)
        bw[ni] = *(const bf16x8*)(Bbase + (size_t)(ni * 16 + li) * 2048 + k0);
      #pragma unroll
      for (int ai = 0; ai < 4; ai++)
        #pragma unroll
        for (int ni = 0; ni < 4; ni++)
          acc[ai][ni] = MFMA_B16(af[ai], bw[ni], acc[ai][ni]);
    }
    #pragma unroll
    for (int ai = 0; ai < 4; ai++)
      #pragma unroll
      for (int ni = 0; ni < 4; ni++)
        #pragma unroll
        for (int rr = 0; rr < 4; rr++)
          red[((w * 64) + ai * 16 + lg * 4 + rr) * 64 + ni * 16 + li] = acc[ai][ni][rr];
    __syncthreads();

    int q = tid >> 2, dbase = (tid & 3) * 16;
    if (q < nvalid){
      int e = myidx[q];
      int tok = e & 1023, r = e >> 10;
      unsigned short* op = qact + ((size_t)((b << 10) + tok) * 4 + r) * 64;
      const float* tp = tab + ((size_t)tok * 32 + (dbase >> 1)) * 2;
      #pragma unroll
      for (int p = 0; p < 8; p++){
        int d0 = dbase + 2 * p;
        float v0 = red[q * 64 + d0]          + red[(64 + q) * 64 + d0]
                 + red[(128 + q) * 64 + d0]  + red[(192 + q) * 64 + d0];
        float v1 = red[q * 64 + d0 + 1]         + red[(64 + q) * 64 + d0 + 1]
                 + red[(128 + q) * 64 + d0 + 1] + red[(192 + q) * 64 + d0 + 1];
        float c = tp[2 * p], s = tp[2 * p + 1];
        op[d0]     = f2bf(v0 * c - v1 * s);
        op[d0 + 1] = f2bf(v0 * s + v1 * c);
      }
    }
  }
}

// ---------------- sparse flash attention; O written IN-PLACE over qact rows ----------------
__global__ __launch_bounds__(256) void attn_sparse_kernel(unsigned short* __restrict__ qact,
                                                          const unsigned short* __restrict__ kbuf,
                                                          const unsigned short* __restrict__ vt,
                                                          const float* __restrict__ gate,
                                                          const unsigned short* __restrict__ idx,
                                                          const int* __restrict__ counts){
  __shared__ unsigned short Ks[64 * 64];
  __shared__ unsigned short Vs[64 * 64];
  __shared__ unsigned short Ps[4][16 * 64];
  const int bh = blockIdx.x, qt = blockIdx.y;
  const int count = counts[bh];
  if (qt * 64 >= count) return;
  const int b = bh >> 5, h = bh & 31;
  const int tid = threadIdx.x, lane = tid & 63, w = tid >> 6;
  const int li = lane & 15, lg = lane >> 4;
  const unsigned short* myidx = idx + bh * 1024 + qt * 64;
  const int nvalid = min(64, count - qt * 64);
  const int qmax = myidx[nvalid - 1] & 1023;

  int qi[4];
  #pragma unroll
  for (int r = 0; r < 4; r++){
    int s = w * 16 + lg * 4 + r;
    qi[r] = (s < nvalid) ? (myidx[s] & 1023) : -1;
  }
  bf16x8 qf0, qf1;
  {
    int s = w * 16 + li;
    int e2 = (s < nvalid) ? myidx[s] : 0;
    const unsigned short* qp = qact + ((size_t)((b << 10) + (e2 & 1023)) * 4 + (e2 >> 10)) * 64;
    qf0 = *(const bf16x8*)(qp + lg * 8);
    qf1 = *(const bf16x8*)(qp + 32 + lg * 8);
  }
  f32x4 o[4];
  #pragma unroll
  for (int i = 0; i < 4; i++) o[i] = f32x4{0.f, 0.f, 0.f, 0.f};
  float m_run[4], l_run[4];
  #pragma unroll
  for (int r = 0; r < 4; r++){ m_run[r] = -1e30f; l_run[r] = 0.f; }

  const int nkt = (qmax >> 6) + 1;
  for (int kt = 0; kt < nkt; kt++){
    const int kb = kt * 64;
    #pragma unroll
    for (int s2 = 0; s2 < 2; s2++){
      int s = s2 * 256 + tid;
      int r = s >> 3, c = (s & 7) * 8;
      gload16(kbuf + (size_t)(b * TT + kb + r) * 2048 + h * 64 + c, &Ks[s * 8]);
      gload16(vt + (size_t)(bh * 64 + r) * TT + kb + c, &Vs[s * 8]);
    }
    __syncthreads();

    f32x4 s4[4];
    #pragma unroll
    for (int ni = 0; ni < 4; ni++){
      bf16x8 k0 = *(const bf16x8*)(&Ks[(ni * 16 + li) * 64 + lg * 8]);
      bf16x8 k1 = *(const bf16x8*)(&Ks[(ni * 16 + li) * 64 + 32 + lg * 8]);
      f32x4 t = f32x4{0.f, 0.f, 0.f, 0.f};
      t = MFMA_B16(qf0, k0, t);
      t = MFMA_B16(qf1, k1, t);
      s4[ni] = t;
    }
    float mt[4];
    #pragma unroll
    for (int r = 0; r < 4; r++) mt[r] = -1e30f;
    #pragma unroll
    for (int ni = 0; ni < 4; ni++){
      int kidx = kb + ni * 16 + li;
      #pragma unroll
      for (int r = 0; r < 4; r++){
        float val = s4[ni][r] * 0.125f;
        val = (kidx <= qi[r]) ? val : -1e30f;
        s4[ni][r] = val;
        mt[r] = fmaxf(mt[r], val);
      }
    }
    #pragma unroll
    for (int r = 0; r < 4; r++){
      #pragma unroll
      for (int sh = 8; sh >= 1; sh >>= 1) mt[r] = fmaxf(mt[r], __shfl_xor(mt[r], sh));
      float mnew = fmaxf(m_run[r], mt[r]);
      float corr = __expf(m_run[r] - mnew);
      m_run[r] = mnew;
      l_run[r] *= corr;
      #pragma unroll
      for (int j = 0; j < 4; j++) o[j][r] *= corr;
    }
    float rs[4] = {0.f, 0.f, 0.f, 0.f};
    #pragma unroll
    for (int ni = 0; ni < 4; ni++)
      #pragma unroll
      for (int r = 0; r < 4; r++){
        float p = __expf(s4[ni][r] - m_run[r]);
        s4[ni][r] = p;
        rs[r] += p;
      }
    #pragma unroll
    for (int r = 0; r < 4; r++){
      #pragma unroll
      for (int sh = 8; sh >= 1; sh >>= 1) rs[r] += __shfl_xor(rs[r], sh);
      l_run[r] += rs[r];
    }
    #pragma unroll
    for (int ni = 0; ni < 4; ni++)
      #pragma unroll
      for (int r = 0; r < 4; r++)
        Ps[w][(lg * 4 + r) * 64 + ni * 16 + li] = f2bf(s4[ni][r]);
    #pragma unroll
    for (int ks = 0; ks < 2; ks++){
      bf16x8 pa = *(const bf16x8*)(&Ps[w][li * 64 + ks * 32 + lg * 8]);
      #pragma unroll
      for (int ni = 0; ni < 4; ni++){
        bf16x8 vb = *(const bf16x8*)(&Vs[(ni * 16 + li) * 64 + ks * 32 + lg * 8]);
        o[ni] = MFMA_B16(pa, vb, o[ni]);
      }
    }
    __syncthreads();
  }
  // epilogue: gate * O / l -> IN PLACE over this row's qact slot
  #pragma unroll
  for (int r = 0; r < 4; r++){
    if (qi[r] < 0) continue;
    float g = gate[(size_t)(b * TT + qi[r]) * 32 + h];
    float inv = g / l_run[r];
    int e = myidx[w * 16 + lg * 4 + r];
    unsigned short* op = qact + ((size_t)((b << 10) + (e & 1023)) * 4 + (e >> 10)) * 64;
    #pragma unroll
    for (int ni = 0; ni < 4; ni++)
      op[ni * 16 + li] = f2bf(o[ni][r] * inv);
  }
}

// ---- block-sparse out-projection, n-split grid: per (bh, qt, nz): 64 O-rows x 256 n-cols ----
__global__ __launch_bounds__(256) void outsp_kernel(const unsigned short* __restrict__ qact,
                                                    const unsigned short* __restrict__ woutT,
                                                    const unsigned short* __restrict__ idx,
                                                    const int* __restrict__ counts,
                                                    unsigned short* __restrict__ p0,
                                                    unsigned short* __restrict__ p1,
                                                    unsigned short* __restrict__ p2,
                                                    unsigned short* __restrict__ p3){
  __shared__ unsigned short As[64 * 64];   // swizzled O rows
  __shared__ unsigned short sidx[64];
  const int bh = blockIdx.x, qt = blockIdx.y;
  const int count = counts[bh];
  if (qt * 64 >= count) return;
  const int b = bh >> 5, h = bh & 31;
  const int tid = threadIdx.x, lane = tid & 63, w = tid >> 6;
  const int li = lane & 15, lg = lane >> 4;
  const int nvalid = min(64, count - qt * 64);
  const unsigned short* myidx = idx + bh * 1024 + qt * 64;
  const int n0 = blockIdx.z * 256 + w * 64;

  bf16x8 bfr[4][2];
  #pragma unroll
  for (int ni = 0; ni < 4; ni++)
    #pragma unroll
    for (int kh = 0; kh < 2; kh++)
      bfr[ni][kh] = *(const bf16x8*)(woutT + (size_t)(n0 + ni * 16 + li) * 2048 + h * 64 + kh * 32 + lg * 8);

  if (tid < 64) sidx[tid] = myidx[(tid < nvalid) ? tid : 0];
  #pragma unroll
  for (int s2 = 0; s2 < 2; s2++){
    int s = s2 * 256 + tid;
    int row = s >> 3, bc = (s & 7) * 16;
    int e = myidx[(row < nvalid) ? row : 0];
    const unsigned short* src = qact + ((size_t)((b << 10) + (e & 1023)) * 4 + (e >> 10)) * 64;
    gload16(src + ((bc ^ ((row & 7) << 4)) >> 1), &As[s * 8]);
  }
  __syncthreads();

  const int kX = (li & 7) << 4;
  f32x4 acc[4][4];
  #pragma unroll
  for (int i = 0; i < 4; i++)
    #pragma unroll
    for (int j = 0; j < 4; j++) acc[i][j] = f32x4{0.f, 0.f, 0.f, 0.f};
  #pragma unroll
  for (int ti = 0; ti < 4; ti++){
    bf16x8 a0 = *(const bf16x8*)(&As[((ti * 16 + li) * 128 + ((lg * 16) ^ kX)) >> 1]);
    bf16x8 a1 = *(const bf16x8*)(&As[((ti * 16 + li) * 128 + ((64 + lg * 16) ^ kX)) >> 1]);
    #pragma unroll
    for (int ni = 0; ni < 4; ni++){
      acc[ti][ni] = MFMA_B16(a0, bfr[ni][0], acc[ti][ni]);
      acc[ti][ni] = MFMA_B16(a1, bfr[ni][1], acc[ti][ni]);
    }
  }
  #pragma unroll
  for (int ti = 0; ti < 4; ti++){
    #pragma unroll
    for (int rr = 0; rr < 4; rr++){
      int slot = ti * 16 + lg * 4 + rr;
      if (slot < nvalid){
        int e = sidx[slot];
        int tok = e & 1023, rk = e >> 10;
        unsigned short* pp = (rk == 0) ? p0 : (rk == 1) ? p1 : (rk == 2) ? p2 : p3;
        size_t base = (size_t)(b * 1024 + tok) * 2048 + n0;
        #pragma unroll
        for (int ni = 0; ni < 4; ni++)
          pp[base + ni * 16 + li] = f2bf(acc[ti][ni][rr]);
      }
    }
  }
}

// ---------------- reduce 4 rank partials (bf16) -> out (fp32) ----------------
__global__ void reduce_kernel(const unsigned short* __restrict__ p0,
                              const unsigned short* __restrict__ p1,
                              const unsigned short* __restrict__ p2,
                              const unsigned short* __restrict__ p3,
                              float* __restrict__ out){
  size_t i = ((size_t)blockIdx.x * 256 + threadIdx.x) * 8;
  u16x8 a = *(const u16x8*)(p0 + i);
  u16x8 b = *(const u16x8*)(p1 + i);
  u16x8 c = *(const u16x8*)(p2 + i);
  u16x8 d = *(const u16x8*)(p3 + i);
  #pragma unroll
  for (int j = 0; j < 8; j++)
    out[i + j] = bf2f(a[j]) + bf2f(b[j]) + bf2f(c[j]) + bf2f(d[j]);
}

extern "C" void kernel_launch(void* const* d_in, const int* in_sizes, int n_in,
                              void* d_out, int out_size, void* d_ws, size_t ws_size,
                              hipStream_t stream){
  const float* x        = (const float*)d_in[0];
  const float* w_router = (const float*)d_in[1];
  const float* w_qkv    = (const float*)d_in[2];
  const float* w_out    = (const float*)d_in[3];
  float* out = (float*)d_out;
  char* ws = (char*)d_ws;

  unsigned short* kbuf   = (unsigned short*)(ws);                       // 16,777,216 [4096][2048]
  unsigned short* vt     = (unsigned short*)(ws + 16777216);            // 16,777,216
  unsigned short* qact   = (unsigned short*)(ws + 33554432);            //  4,194,304 [4096tok][4r][64]
  unsigned short* idx    = (unsigned short*)(ws + 37748736);            //    262,144
  int* counts            = (int*)(ws + 38010880);                       //        512
  unsigned char* heads4  = (unsigned char*)(ws + 38011392);             //     16,384
  unsigned short* x_bf   = (unsigned short*)(ws + 50331648);            // 16,777,216
  unsigned short* wqkvT  = (unsigned short*)(ws + 67108864);            // 25,165,824
  unsigned short* woutT  = (unsigned short*)(ws + 92274688);            //  8,388,608
  float* gate            = (float*)(ws + 100663296);                    //    524,288
  float* tab             = (float*)(ws + 101187584);                    //    262,144
  unsigned short* part0  = kbuf;                                        // dead after attn
  unsigned short* part1  = vt;                                          // dead after attn
  unsigned short* part2  = x_bf;                                        // dead after super
  unsigned short* part3  = wqkvT;                                       // dead after super (first 16.7MB)

  constexpr int KV_LDS = 73728;   // 3-slot ring (also covers qgemm path's 64KB red[])
  (void)hipFuncSetAttribute(reinterpret_cast<const void*>(&super_kernel),
                            hipFuncAttributeMaxDynamicSharedMemorySize, KV_LDS);

  // 1: prep (512 blocks) + weight transposes (16384 blocks)
  hipLaunchKernelGGL(prep2_kernel, dim3(16896), dim3(256), 0, stream,
                     x, w_router, w_qkv, w_out, x_bf, gate, heads4, tab, wqkvT, woutT);
  // 2: compaction
  hipLaunchKernelGGL(compact_kernel, dim3(128), dim3(64), 0, stream, heads4, idx, counts);
  // 3: KV GEMM (512 blocks) + sparse Q GEMM (2048 blocks) co-scheduled
  hipLaunchKernelGGL(super_kernel, dim3(2560), dim3(256), KV_LDS, stream,
                     x_bf, wqkvT, kbuf, vt, tab, idx, counts, qact);
  // 4: flash attention; O overwrites qact in place
  hipLaunchKernelGGL(attn_sparse_kernel, dim3(128, 16), dim3(256), 0, stream,
                     qact, kbuf, vt, gate, idx, counts);
  // 5: block-sparse out-projection into rank partials
  hipLaunchKernelGGL(outsp_kernel, dim3(128, 16, 8), dim3(256), 0, stream,
                     qact, woutT, idx, counts, part0, part1, part2, part3);
  // 6: sum partials -> fp32 out
  hipLaunchKernelGGL(reduce_kernel, dim3(4096), dim3(256), 0, stream,
                     part0, part1, part2, part3, out);
}

// Round 15
// 241.142 us; speedup vs baseline: 1.3677x; 1.3677x over previous
//
#include <hip/hip_runtime.h>
#include <hip/hip_bf16.h>
#include <stdint.h>
#include <stddef.h>

typedef __attribute__((ext_vector_type(8))) short bf16x8;       // 4-VGPR MFMA A/B frag (8 bf16)
typedef __attribute__((ext_vector_type(8))) unsigned short u16x8;
typedef __attribute__((ext_vector_type(4))) float f32x4;
typedef __attribute__((ext_vector_type(16))) float f32x16;      // 32x32 MFMA C/D frag

#define TT 1024

__device__ __forceinline__ unsigned short f2bf(float f){
  unsigned u = __builtin_bit_cast(unsigned, f);
  unsigned r = 0x7fffu + ((u >> 16) & 1u);
  return (unsigned short)((u + r) >> 16);
}
__device__ __forceinline__ float bf2f(unsigned short s){
  unsigned u = ((unsigned)s) << 16;
  return __builtin_bit_cast(float, u);
}
// async global->LDS, 16B per lane. LDS dest must be tid-linear (base + lane*16).
__device__ __forceinline__ void gload16(const unsigned short* g, unsigned short* l){
  __builtin_amdgcn_global_load_lds(
      (const __attribute__((address_space(1))) void*)g,
      (__attribute__((address_space(3))) void*)l, 16, 0, 0);
}

#define MFMA32(a, b, c) __builtin_amdgcn_mfma_f32_32x32x16_bf16((a), (b), (c), 0, 0, 0)
#define MFMA_B16(a, b, c) __builtin_amdgcn_mfma_f32_16x16x32_bf16((a), (b), (c), 0, 0, 0)

// ==== prep2: blocks 0..511 = x-cast + router + rope-table;  512..16895 = weight transposes ====
// (data-disjoint block-range fusion; both paths byte-identical math to their standalone forms)
__global__ __launch_bounds__(256) void prep2_kernel(const float* __restrict__ x,
                                                    const float* __restrict__ wr,
                                                    const float* __restrict__ wqkv,
                                                    const float* __restrict__ wout,
                                                    unsigned short* __restrict__ x_bf,
                                                    float* __restrict__ gate,
                                                    unsigned char* __restrict__ heads4,
                                                    float* __restrict__ tab,
                                                    unsigned short* __restrict__ wqkvT,
                                                    unsigned short* __restrict__ woutT){
  __shared__ float xc[8 * 256];
  __shared__ float red[8 * 8 * 32];
  __shared__ float tile[32][33];
  const int tid = threadIdx.x;

  if (blockIdx.x >= 512){
    int tb = blockIdx.x - 512;            // 0..16383
    int bx = tb & 255, by = tb >> 8;
    const float* in; unsigned short* out; int C;
    if (bx < 192){ in = wqkv; out = wqkvT; C = 6144; }
    else         { in = wout; out = woutT; C = 2048; bx -= 192; }
    const int R = 2048;
    int c0 = bx * 32, r0 = by * 32;
    int tx = tid & 31, ty = tid >> 5;
    for (int i = ty; i < 32; i += 8)
      tile[i][tx] = in[(size_t)(r0 + i) * C + c0 + tx];
    __syncthreads();
    for (int i = ty; i < 32; i += 8)
      out[(size_t)(c0 + i) * R + r0 + tx] = f2bf(tile[tx][i]);
    return;
  }

  const int tok0 = blockIdx.x * 8;
  const int p = tid >> 5, h = tid & 31;

  if (blockIdx.x < 128){
    int i2 = blockIdx.x * 256 + tid;
    int pos = i2 >> 5, ii = i2 & 31;
    float freq = powf(10000.0f, -(float)ii / 32.0f);
    float ang = (float)pos * freq;
    tab[i2 * 2]     = cosf(ang);
    tab[i2 * 2 + 1] = sinf(ang);
  }

  float acc[8] = {0.f,0.f,0.f,0.f,0.f,0.f,0.f,0.f};
  for (int kb = 0; kb < 8; kb++){
    __syncthreads();
    {
      int tok = tid >> 5, e = (tid & 31) * 8;
      const float* xp = x + (size_t)(tok0 + tok) * 2048 + kb * 256 + e;
      float4 v0 = *(const float4*)xp, v1 = *(const float4*)(xp + 4);
      float vals[8] = {v0.x, v0.y, v0.z, v0.w, v1.x, v1.y, v1.z, v1.w};
      u16x8 ob;
      #pragma unroll
      for (int jj = 0; jj < 8; jj++) ob[jj] = f2bf(vals[jj]);
      *(u16x8*)(x_bf + (size_t)(tok0 + tok) * 2048 + kb * 256 + e) = ob;
      #pragma unroll
      for (int jj = 0; jj < 8; jj++) xc[tok * 256 + e + jj] = vals[jj];
    }
    __syncthreads();
    const float* wp = wr + (size_t)(kb * 256 + p * 32) * 32 + h;
    #pragma unroll 4
    for (int j = 0; j < 32; j++){
      float wv = wp[j * 32];
      #pragma unroll
      for (int tok = 0; tok < 8; tok++)
        acc[tok] += xc[tok * 256 + p * 32 + j] * wv;
    }
  }
  #pragma unroll
  for (int tok = 0; tok < 8; tok++) red[(p * 8 + tok) * 32 + h] = acc[tok];
  __syncthreads();
  {
    int lane = tid & 63;
    int tok = (tid >> 6) * 2 + (lane >> 5);
    int hh = lane & 31;
    float logit = 0.f;
    #pragma unroll
    for (int pp = 0; pp < 8; pp++) logit += red[(pp * 8 + tok) * 32 + hh];
    float m = logit;
    #pragma unroll
    for (int s = 16; s >= 1; s >>= 1) m = fmaxf(m, __shfl_xor(m, s));
    float e = __expf(logit - m);
    float sum = e;
    #pragma unroll
    for (int s = 16; s >= 1; s >>= 1) sum += __shfl_xor(sum, s);
    float prob = e / sum;
    float v = logit; int sel = 0;
    #pragma unroll
    for (int rr2 = 0; rr2 < 4; rr2++){
      float bv = v; int bi = hh;
      #pragma unroll
      for (int s = 16; s >= 1; s >>= 1){
        float ov = __shfl_xor(bv, s); int oi = __shfl_xor(bi, s);
        if (ov > bv || (ov == bv && oi < bi)) { bv = ov; bi = oi; }
      }
      if (hh == bi) { sel = 1; v = -3.4e38f; }
    }
    gate[(size_t)(tok0 + tok) * 32 + hh] = sel ? prob : 0.f;
    unsigned long long bal = __ballot(sel != 0);
    unsigned selmask = (unsigned)(bal >> ((lane >> 5) * 32));
    if (sel){
      int r = __popc(selmask & ((1u << hh) - 1u));
      heads4[(size_t)(tok0 + tok) * 4 + r] = (unsigned char)hh;
    }
  }
}

// ------- per-(b,h) active-token compaction; entry = tok | (rank<<10), order-preserving -------
__global__ void compact_kernel(const unsigned char* __restrict__ heads4,
                               unsigned short* __restrict__ idx, int* __restrict__ counts){
  int bh = blockIdx.x;
  int b = bh >> 5, h = bh & 31;
  int lane = threadIdx.x;
  int base = 0;
  for (int c = 0; c < 16; c++){
    int t = c * 64 + lane;
    unsigned u = ((const unsigned*)heads4)[b * 1024 + t];
    int r = -1;
    if (((u      ) & 255) == (unsigned)h) r = 0;
    else if (((u >>  8) & 255) == (unsigned)h) r = 1;
    else if (((u >> 16) & 255) == (unsigned)h) r = 2;
    else if (((u >> 24) & 255) == (unsigned)h) r = 3;
    bool act = (r >= 0);
    unsigned long long mask = __ballot(act);
    int pos = base + __popcll(mask & ((1ull << lane) - 1ull));
    if (act) idx[bh * 1024 + pos] = (unsigned short)(t | (r << 10));
    base += __popcll(mask);
  }
  if (lane == 0) counts[bh] = base;
}

// ---------------- sparse Q GEMM + RoPE: per (bh, qt), 4 waves K-split ----------------
__global__ __launch_bounds__(256) void qgemm_kernel(const unsigned short* __restrict__ x_bf,
                                                    const unsigned short* __restrict__ wqkvT,
                                                    const unsigned short* __restrict__ idx,
                                                    const int* __restrict__ counts,
                                                    const float* __restrict__ tab,
                                                    unsigned short* __restrict__ qact){
  __shared__ float red[4][64][64];   // 64 KB
  const int bh = blockIdx.x, qt = blockIdx.y;
  const int count = counts[bh];
  if (qt * 64 >= count) return;
  const int b = bh >> 5, h = bh & 31;
  const int tid = threadIdx.x, lane = tid & 63, w = tid >> 6;
  const int li = lane & 15, lg = lane >> 4;
  const int nvalid = min(64, count - qt * 64);
  const unsigned short* myidx = idx + bh * 1024 + qt * 64;

  int atok[4];
  #pragma unroll
  for (int ai = 0; ai < 4; ai++){
    int s = ai * 16 + li;
    atok[ai] = (s < nvalid) ? (myidx[s] & 1023) : 0;
  }
  const unsigned short* Bbase = wqkvT + (size_t)(h * 64) * 2048;

  f32x4 acc[4][4];
  #pragma unroll
  for (int i = 0; i < 4; i++)
    #pragma unroll
    for (int j = 0; j < 4; j++) acc[i][j] = f32x4{0.f, 0.f, 0.f, 0.f};

  const int k0w = w * 512;
  #pragma unroll 2
  for (int ks = 0; ks < 16; ks++){
    int k0 = k0w + ks * 32 + lg * 8;
    bf16x8 af[4], bw[4];
    #pragma unroll
    for (int ai = 0; ai < 4; ai++)
      af[ai] = *(const bf16x8*)(x_bf + (size_t)(b * 1024 + atok[ai]) * 2048 + k0);
    #pragma unroll
    for (int ni = 0; ni < 4; ni++)
      bw[ni] = *(const bf16x8*)(Bbase + (size_t)(ni * 16 + li) * 2048 + k0);
    #pragma unroll
    for (int ai = 0; ai < 4; ai++)
      #pragma unroll
      for (int ni = 0; ni < 4; ni++)
        acc[ai][ni] = MFMA_B16(af[ai], bw[ni], acc[ai][ni]);
  }
  #pragma unroll
  for (int ai = 0; ai < 4; ai++)
    #pragma unroll
    for (int ni = 0; ni < 4; ni++)
      #pragma unroll
      for (int rr = 0; rr < 4; rr++)
        red[w][ai * 16 + lg * 4 + rr][ni * 16 + li] = acc[ai][ni][rr];
  __syncthreads();

  int q = tid >> 2, dbase = (tid & 3) * 16;
  if (q < nvalid){
    int e = myidx[q];
    int tok = e & 1023, r = e >> 10;
    unsigned short* op = qact + ((size_t)((b << 10) + tok) * 4 + r) * 64;
    const float* tp = tab + ((size_t)tok * 32 + (dbase >> 1)) * 2;
    #pragma unroll
    for (int p = 0; p < 8; p++){
      int d0 = dbase + 2 * p;
      float v0 = red[0][q][d0] + red[1][q][d0] + red[2][q][d0] + red[3][q][d0];
      float v1 = red[0][q][d0 + 1] + red[1][q][d0 + 1] + red[2][q][d0 + 1] + red[3][q][d0 + 1];
      float c = tp[2 * p], s = tp[2 * p + 1];
      op[d0]     = f2bf(v0 * c - v1 * s);
      op[d0 + 1] = f2bf(v0 * s + v1 * c);
    }
  }
}

// ======== 32x32x16 KV GEMM, BK=32, 3-slot ring, 2 blocks/CU.  BM=256, BN=128. ========
// A packed in LDS as [BM/2 lines][128B], swizzle byte ^= (line&7)<<4.
// bn<16: RoPE'd K -> kbuf; bn>=16: V^T -> vt.
__global__ __launch_bounds__(256, 2) void gemmk(const unsigned short* __restrict__ A,
                                                const unsigned short* __restrict__ Bt,
                                                unsigned short* __restrict__ kbuf,
                                                unsigned short* __restrict__ vt,
                                                const float* __restrict__ tab,
                                                int K, int nbm){
  extern __shared__ unsigned short smem[];
  constexpr int MREP = 4;
  constexpr int BM = MREP * 64;
  constexpr int AU = MREP * 2048;
  constexpr int SLOT = AU + 4096;
  const int nblk = gridDim.x;
  const int raw = blockIdx.x;
  const int tile = (raw & 7) * (nblk >> 3) + (raw >> 3);
  const int bn = tile / nbm, bm = tile % nbm;

  const int tid = threadIdx.x, lane = tid & 63, wid = tid >> 6;
  const int wrow = wid >> 1, wcol = wid & 1;
  const int l31 = lane & 31, hi = lane >> 5;
  const int X = ((l31 >> 1) & 7) << 4;

  const unsigned short* gA[MREP];
  const unsigned short* gB[2];
  #pragma unroll
  for (int p = 0; p < MREP; p++){
    int L = tid * 16 + p * 4096;
    int line = L >> 7;
    int cs = (L & 127) ^ ((line & 7) << 4);
    gA[p] = A + (size_t)(bm * BM + line * 2 + (cs >> 6)) * K + ((cs & 63) >> 1);
  }
  #pragma unroll
  for (int p = 0; p < 2; p++){
    int L = tid * 16 + p * 4096;
    int line = L >> 7;
    int cs = (L & 127) ^ ((line & 7) << 4);
    gB[p] = Bt + (size_t)(bn * 128 + line * 2 + (cs >> 6)) * K + ((cs & 63) >> 1);
  }

  f32x16 acc[MREP][2];
  #pragma unroll
  for (int i = 0; i < MREP; i++)
    #pragma unroll
    for (int j = 0; j < 2; j++) acc[i][j] = f32x16{0,0,0,0,0,0,0,0,0,0,0,0,0,0,0,0};

  const int NT = K >> 5;   // BK = 32
  #pragma unroll
  for (int tt = 0; tt < 2; tt++){
    unsigned short* sb = smem + tt * SLOT;
    #pragma unroll
    for (int p = 0; p < MREP; p++) gload16(gA[p] + (size_t)tt * 32, sb + tid * 8 + p * 2048);
    #pragma unroll
    for (int p = 0; p < 2; p++)    gload16(gB[p] + (size_t)tt * 32, sb + AU + tid * 8 + p * 2048);
  }

  for (int t = 0; t < NT; ++t){
    if (t < NT - 1) asm volatile("s_waitcnt vmcnt(6)" ::: "memory");
    else            asm volatile("s_waitcnt vmcnt(0)" ::: "memory");
    __builtin_amdgcn_s_barrier();
    __builtin_amdgcn_sched_barrier(0);
    const unsigned short* bs = smem + (t % 3) * SLOT;
    unsigned short* ns = smem + ((t + 2) % 3) * SLOT;
    const bool st = (t + 2 < NT);
    #pragma unroll
    for (int ks = 0; ks < 2; ks++){
      const int bo = (((l31 & 1) * 64 + ks * 32 + hi * 16) ^ X) >> 1;
      bf16x8 av[MREP], bv[2];
      #pragma unroll
      for (int i = 0; i < MREP; i++)
        av[i] = *(const bf16x8*)(bs + (wrow * (MREP * 16) + i * 16 + (l31 >> 1)) * 64 + bo);
      #pragma unroll
      for (int j = 0; j < 2; j++)
        bv[j] = *(const bf16x8*)(bs + AU + (wcol * 32 + j * 16 + (l31 >> 1)) * 64 + bo);
      if (st){
        if (ks == 0){
          #pragma unroll
          for (int p = 0; p < 3; p++)
            gload16(gA[p] + (size_t)(t + 2) * 32, ns + tid * 8 + p * 2048);
        } else {
          gload16(gA[3] + (size_t)(t + 2) * 32, ns + tid * 8 + 3 * 2048);
          #pragma unroll
          for (int p = 0; p < 2; p++)
            gload16(gB[p] + (size_t)(t + 2) * 32, ns + AU + tid * 8 + p * 2048);
        }
      }
      #pragma unroll
      for (int i = 0; i < MREP; i++){
        acc[i][0] = MFMA32(av[i], bv[0], acc[i][0]);
        acc[i][1] = MFMA32(av[i], bv[1], acc[i][1]);
      }
    }
  }

  // 32x32 C/D: col = lane&31, row = (reg&3) + 8*(reg>>2) + 4*(lane>>5)
  if (bn < 16){
    #pragma unroll
    for (int i = 0; i < MREP; i++){
      #pragma unroll
      for (int j = 0; j < 2; j++){
        int col = bn * 128 + wcol * 64 + j * 32 + l31;
        int ii = (col & 63) >> 1;
        #pragma unroll
        for (int g = 0; g < 4; g++){
          #pragma unroll
          for (int rr = 0; rr < 4; rr++){
            int row = bm * BM + wrow * (BM / 2) + i * 32 + g * 8 + hi * 4 + rr;
            int pos = row & (TT - 1);
            const float* tp = tab + ((size_t)pos * 32 + ii) * 2;
            float c = tp[0], s = tp[1];
            float val = acc[i][j][g * 4 + rr];
            float pv = __shfl_xor(val, 1);
            float res = (lane & 1) ? (pv * s + val * c) : (val * c - pv * s);
            kbuf[(size_t)row * 2048 + col] = f2bf(res);
          }
        }
      }
    }
  } else {
    #pragma unroll
    for (int i = 0; i < MREP; i++){
      #pragma unroll
      for (int j = 0; j < 2; j++){
        int vcol = bn * 128 + wcol * 64 + j * 32 + l31 - 2048;
        int hh = vcol >> 6, d = vcol & 63;
        int row0 = bm * BM + wrow * (BM / 2) + i * 32 + hi * 4;
        int b = row0 >> 10, t0 = row0 & (TT - 1);
        #pragma unroll
        for (int g = 0; g < 4; g++){
          ushort4 pk;
          pk.x = f2bf(acc[i][j][g * 4 + 0]); pk.y = f2bf(acc[i][j][g * 4 + 1]);
          pk.z = f2bf(acc[i][j][g * 4 + 2]); pk.w = f2bf(acc[i][j][g * 4 + 3]);
          *(ushort4*)(vt + ((size_t)((b * 32 + hh) * 64 + d)) * TT + t0 + g * 8) = pk;
        }
      }
    }
  }
}

// ---------------- sparse flash attention; O written IN-PLACE over qact rows ----------------
__global__ __launch_bounds__(256) void attn_sparse_kernel(unsigned short* __restrict__ qact,
                                                          const unsigned short* __restrict__ kbuf,
                                                          const unsigned short* __restrict__ vt,
                                                          const float* __restrict__ gate,
                                                          const unsigned short* __restrict__ idx,
                                                          const int* __restrict__ counts){
  __shared__ unsigned short Ks[64 * 64];
  __shared__ unsigned short Vs[64 * 64];
  __shared__ unsigned short Ps[4][16 * 64];
  const int bh = blockIdx.x, qt = blockIdx.y;
  const int count = counts[bh];
  if (qt * 64 >= count) return;
  const int b = bh >> 5, h = bh & 31;
  const int tid = threadIdx.x, lane = tid & 63, w = tid >> 6;
  const int li = lane & 15, lg = lane >> 4;
  const unsigned short* myidx = idx + bh * 1024 + qt * 64;
  const int nvalid = min(64, count - qt * 64);
  const int qmax = myidx[nvalid - 1] & 1023;

  int qi[4];
  #pragma unroll
  for (int r = 0; r < 4; r++){
    int s = w * 16 + lg * 4 + r;
    qi[r] = (s < nvalid) ? (myidx[s] & 1023) : -1;
  }
  bf16x8 qf0, qf1;
  {
    int s = w * 16 + li;
    int e2 = (s < nvalid) ? myidx[s] : 0;
    const unsigned short* qp = qact + ((size_t)((b << 10) + (e2 & 1023)) * 4 + (e2 >> 10)) * 64;
    qf0 = *(const bf16x8*)(qp + lg * 8);
    qf1 = *(const bf16x8*)(qp + 32 + lg * 8);
  }
  f32x4 o[4];
  #pragma unroll
  for (int i = 0; i < 4; i++) o[i] = f32x4{0.f, 0.f, 0.f, 0.f};
  float m_run[4], l_run[4];
  #pragma unroll
  for (int r = 0; r < 4; r++){ m_run[r] = -1e30f; l_run[r] = 0.f; }

  const int nkt = (qmax >> 6) + 1;
  for (int kt = 0; kt < nkt; kt++){
    const int kb = kt * 64;
    #pragma unroll
    for (int s2 = 0; s2 < 2; s2++){
      int s = s2 * 256 + tid;
      int r = s >> 3, c = (s & 7) * 8;
      gload16(kbuf + (size_t)(b * TT + kb + r) * 2048 + h * 64 + c, &Ks[s * 8]);
      gload16(vt + (size_t)(bh * 64 + r) * TT + kb + c, &Vs[s * 8]);
    }
    __syncthreads();

    f32x4 s4[4];
    #pragma unroll
    for (int ni = 0; ni < 4; ni++){
      bf16x8 k0 = *(const bf16x8*)(&Ks[(ni * 16 + li) * 64 + lg * 8]);
      bf16x8 k1 = *(const bf16x8*)(&Ks[(ni * 16 + li) * 64 + 32 + lg * 8]);
      f32x4 t = f32x4{0.f, 0.f, 0.f, 0.f};
      t = MFMA_B16(qf0, k0, t);
      t = MFMA_B16(qf1, k1, t);
      s4[ni] = t;
    }
    float mt[4];
    #pragma unroll
    for (int r = 0; r < 4; r++) mt[r] = -1e30f;
    #pragma unroll
    for (int ni = 0; ni < 4; ni++){
      int kidx = kb + ni * 16 + li;
      #pragma unroll
      for (int r = 0; r < 4; r++){
        float val = s4[ni][r] * 0.125f;
        val = (kidx <= qi[r]) ? val : -1e30f;
        s4[ni][r] = val;
        mt[r] = fmaxf(mt[r], val);
      }
    }
    #pragma unroll
    for (int r = 0; r < 4; r++){
      #pragma unroll
      for (int sh = 8; sh >= 1; sh >>= 1) mt[r] = fmaxf(mt[r], __shfl_xor(mt[r], sh));
      float mnew = fmaxf(m_run[r], mt[r]);
      float corr = __expf(m_run[r] - mnew);
      m_run[r] = mnew;
      l_run[r] *= corr;
      #pragma unroll
      for (int j = 0; j < 4; j++) o[j][r] *= corr;
    }
    float rs[4] = {0.f, 0.f, 0.f, 0.f};
    #pragma unroll
    for (int ni = 0; ni < 4; ni++)
      #pragma unroll
      for (int r = 0; r < 4; r++){
        float p = __expf(s4[ni][r] - m_run[r]);
        s4[ni][r] = p;
        rs[r] += p;
      }
    #pragma unroll
    for (int r = 0; r < 4; r++){
      #pragma unroll
      for (int sh = 8; sh >= 1; sh >>= 1) rs[r] += __shfl_xor(rs[r], sh);
      l_run[r] += rs[r];
    }
    #pragma unroll
    for (int ni = 0; ni < 4; ni++)
      #pragma unroll
      for (int r = 0; r < 4; r++)
        Ps[w][(lg * 4 + r) * 64 + ni * 16 + li] = f2bf(s4[ni][r]);
    #pragma unroll
    for (int ks = 0; ks < 2; ks++){
      bf16x8 pa = *(const bf16x8*)(&Ps[w][li * 64 + ks * 32 + lg * 8]);
      #pragma unroll
      for (int ni = 0; ni < 4; ni++){
        bf16x8 vb = *(const bf16x8*)(&Vs[(ni * 16 + li) * 64 + ks * 32 + lg * 8]);
        o[ni] = MFMA_B16(pa, vb, o[ni]);
      }
    }
    __syncthreads();
  }
  // epilogue: gate * O / l -> IN PLACE over this row's qact slot
  #pragma unroll
  for (int r = 0; r < 4; r++){
    if (qi[r] < 0) continue;
    float g = gate[(size_t)(b * TT + qi[r]) * 32 + h];
    float inv = g / l_run[r];
    int e = myidx[w * 16 + lg * 4 + r];
    unsigned short* op = qact + ((size_t)((b << 10) + (e & 1023)) * 4 + (e >> 10)) * 64;
    #pragma unroll
    for (int ni = 0; ni < 4; ni++)
      op[ni * 16 + li] = f2bf(o[ni][r] * inv);
  }
}

// ---- block-sparse out-projection, n-split grid: per (bh, qt, nz): 64 O-rows x 256 n-cols ----
__global__ __launch_bounds__(256) void outsp_kernel(const unsigned short* __restrict__ qact,
                                                    const unsigned short* __restrict__ woutT,
                                                    const unsigned short* __restrict__ idx,
                                                    const int* __restrict__ counts,
                                                    unsigned short* __restrict__ p0,
                                                    unsigned short* __restrict__ p1,
                                                    unsigned short* __restrict__ p2,
                                                    unsigned short* __restrict__ p3){
  __shared__ unsigned short As[64 * 64];   // swizzled O rows
  __shared__ unsigned short sidx[64];
  const int bh = blockIdx.x, qt = blockIdx.y;
  const int count = counts[bh];
  if (qt * 64 >= count) return;
  const int b = bh >> 5, h = bh & 31;
  const int tid = threadIdx.x, lane = tid & 63, w = tid >> 6;
  const int li = lane & 15, lg = lane >> 4;
  const int nvalid = min(64, count - qt * 64);
  const unsigned short* myidx = idx + bh * 1024 + qt * 64;
  const int n0 = blockIdx.z * 256 + w * 64;

  bf16x8 bfr[4][2];
  #pragma unroll
  for (int ni = 0; ni < 4; ni++)
    #pragma unroll
    for (int kh = 0; kh < 2; kh++)
      bfr[ni][kh] = *(const bf16x8*)(woutT + (size_t)(n0 + ni * 16 + li) * 2048 + h * 64 + kh * 32 + lg * 8);

  if (tid < 64) sidx[tid] = myidx[(tid < nvalid) ? tid : 0];
  #pragma unroll
  for (int s2 = 0; s2 < 2; s2++){
    int s = s2 * 256 + tid;
    int row = s >> 3, bc = (s & 7) * 16;
    int e = myidx[(row < nvalid) ? row : 0];
    const unsigned short* src = qact + ((size_t)((b << 10) + (e & 1023)) * 4 + (e >> 10)) * 64;
    gload16(src + ((bc ^ ((row & 7) << 4)) >> 1), &As[s * 8]);
  }
  __syncthreads();

  const int kX = (li & 7) << 4;
  f32x4 acc[4][4];
  #pragma unroll
  for (int i = 0; i < 4; i++)
    #pragma unroll
    for (int j = 0; j < 4; j++) acc[i][j] = f32x4{0.f, 0.f, 0.f, 0.f};
  #pragma unroll
  for (int ti = 0; ti < 4; ti++){
    bf16x8 a0 = *(const bf16x8*)(&As[((ti * 16 + li) * 128 + ((lg * 16) ^ kX)) >> 1]);
    bf16x8 a1 = *(const bf16x8*)(&As[((ti * 16 + li) * 128 + ((64 + lg * 16) ^ kX)) >> 1]);
    #pragma unroll
    for (int ni = 0; ni < 4; ni++){
      acc[ti][ni] = MFMA_B16(a0, bfr[ni][0], acc[ti][ni]);
      acc[ti][ni] = MFMA_B16(a1, bfr[ni][1], acc[ti][ni]);
    }
  }
  #pragma unroll
  for (int ti = 0; ti < 4; ti++){
    #pragma unroll
    for (int rr = 0; rr < 4; rr++){
      int slot = ti * 16 + lg * 4 + rr;
      if (slot < nvalid){
        int e = sidx[slot];
        int tok = e & 1023, rk = e >> 10;
        unsigned short* pp = (rk == 0) ? p0 : (rk == 1) ? p1 : (rk == 2) ? p2 : p3;
        size_t base = (size_t)(b * 1024 + tok) * 2048 + n0;
        #pragma unroll
        for (int ni = 0; ni < 4; ni++)
          pp[base + ni * 16 + li] = f2bf(acc[ti][ni][rr]);
      }
    }
  }
}

// ---------------- reduce 4 rank partials (bf16) -> out (fp32) ----------------
__global__ void reduce_kernel(const unsigned short* __restrict__ p0,
                              const unsigned short* __restrict__ p1,
                              const unsigned short* __restrict__ p2,
                              const unsigned short* __restrict__ p3,
                              float* __restrict__ out){
  size_t i = ((size_t)blockIdx.x * 256 + threadIdx.x) * 8;
  u16x8 a = *(const u16x8*)(p0 + i);
  u16x8 b = *(const u16x8*)(p1 + i);
  u16x8 c = *(const u16x8*)(p2 + i);
  u16x8 d = *(const u16x8*)(p3 + i);
  #pragma unroll
  for (int j = 0; j < 8; j++)
    out[i + j] = bf2f(a[j]) + bf2f(b[j]) + bf2f(c[j]) + bf2f(d[j]);
}

extern "C" void kernel_launch(void* const* d_in, const int* in_sizes, int n_in,
                              void* d_out, int out_size, void* d_ws, size_t ws_size,
                              hipStream_t stream){
  const float* x        = (const float*)d_in[0];
  const float* w_router = (const float*)d_in[1];
  const float* w_qkv    = (const float*)d_in[2];
  const float* w_out    = (const float*)d_in[3];
  float* out = (float*)d_out;
  char* ws = (char*)d_ws;

  unsigned short* kbuf   = (unsigned short*)(ws);                       // 16,777,216 [4096][2048]
  unsigned short* vt     = (unsigned short*)(ws + 16777216);            // 16,777,216
  unsigned short* qact   = (unsigned short*)(ws + 33554432);            //  4,194,304 [4096tok][4r][64]
  unsigned short* idx    = (unsigned short*)(ws + 37748736);            //    262,144
  int* counts            = (int*)(ws + 38010880);                       //        512
  unsigned char* heads4  = (unsigned char*)(ws + 38011392);             //     16,384
  unsigned short* x_bf   = (unsigned short*)(ws + 50331648);            // 16,777,216
  unsigned short* wqkvT  = (unsigned short*)(ws + 67108864);            // 25,165,824
  unsigned short* woutT  = (unsigned short*)(ws + 92274688);            //  8,388,608
  float* gate            = (float*)(ws + 100663296);                    //    524,288
  float* tab             = (float*)(ws + 101187584);                    //    262,144
  unsigned short* part0  = kbuf;                                        // dead after attn
  unsigned short* part1  = vt;                                          // dead after attn
  unsigned short* part2  = x_bf;                                        // dead after qgemm
  unsigned short* part3  = wqkvT;                                       // dead after qgemm (first 16.7MB)

  constexpr int KV_LDS = 73728;   // 3-slot ring
  (void)hipFuncSetAttribute(reinterpret_cast<const void*>(&gemmk),
                            hipFuncAttributeMaxDynamicSharedMemorySize, KV_LDS);

  // 1: prep (512 blocks) + weight transposes (16384 blocks), data-disjoint
  hipLaunchKernelGGL(prep2_kernel, dim3(16896), dim3(256), 0, stream,
                     x, w_router, w_qkv, w_out, x_bf, gate, heads4, tab, wqkvT, woutT);
  // 2: compaction
  hipLaunchKernelGGL(compact_kernel, dim3(128), dim3(64), 0, stream, heads4, idx, counts);
  // 3: KV GEMM (standalone, round-13 proven): grid 512 = 2 blocks/CU
  hipLaunchKernelGGL(gemmk, dim3(512), dim3(256), KV_LDS, stream,
                     x_bf, wqkvT + (size_t)2048 * 2048, kbuf, vt, tab, 2048, 16);
  // 4: sparse Q GEMM (standalone, round-13 proven)
  hipLaunchKernelGGL(qgemm_kernel, dim3(128, 16), dim3(256), 0, stream,
                     x_bf, wqkvT, idx, counts, tab, qact);
  // 5: flash attention; O overwrites qact in place
  hipLaunchKernelGGL(attn_sparse_kernel, dim3(128, 16), dim3(256), 0, stream,
                     qact, kbuf, vt, gate, idx, counts);
  // 6: block-sparse out-projection into rank partials
  hipLaunchKernelGGL(outsp_kernel, dim3(128, 16, 8), dim3(256), 0, stream,
                     qact, woutT, idx, counts, part0, part1, part2, part3);
  // 7: sum partials -> fp32 out
  hipLaunchKernelGGL(reduce_kernel, dim3(4096), dim3(256), 0, stream,
                     part0, part1, part2, part3, out);
}